// Round 9
// baseline (68.703 us; speedup 1.0000x reference)
//
#include <hip/hip_runtime.h>

#define NB 16
#define HH 1024
#define WW 1024
#define TW 128         // block tile width  (32 col-groups * 4)
#define TH 32          // block tile height (8 row-groups * 4)

#define EPS1 2e-4f     // edge-threshold confidence margin (f32 err bound ~2e-6)
#define EPS2 1e-4f     // final-threshold confidence margin (f32 err bound ~3e-6)

typedef float f32x4 __attribute__((ext_vector_type(4)));

// Cold exact-path: recompute one pixel in f64 straight from global memory
// (same math as the R1/R6 kernels that scored absmax 0.0 vs the np reference).
__device__ __noinline__ float aes_exact_g(const float* __restrict__ m,
                                          int gy, int gx,
                                          float bsf, float esf, float fthr)
{
    const double bfd   = (double)bsf / 3.0;
    const double ethrd = 0.5 * (double)esf;
    const double fthrd = (double)fthr;
    const double w25d  = (double)(1.0f / 25.0f);

    double s25 = 0.0, s9 = 0.0;
    for (int dy = -2; dy <= 2; ++dy)
        for (int dx = -2; dx <= 2; ++dx) {
            int yy = gy + dy, xx = gx + dx;
            double v = 0.0;
            if ((unsigned)yy < (unsigned)HH && (unsigned)xx < (unsigned)WW)
                v = (double)m[(size_t)yy * WW + xx];
            s25 += v;
            if (dy >= -1 && dy <= 1 && dx >= -1 && dx <= 1) s9 += v;
        }
    double c      = (double)m[(size_t)gy * WW + gx];
    double edges  = fabs(9.0 * c - s9);
    double sbase  = s25 * w25d;
    double smooth = c * (1.0 - bfd) + sbase * bfd;
    double result = (edges > ethrd) ? smooth : c;
    return (result > fthrd) ? 1.0f : 0.0f;
}

__global__ __launch_bounds__(256, 3)
void aes_kernel(const float* __restrict__ mask,
                const float* __restrict__ blur_strength,
                const float* __restrict__ edge_sensitivity,
                const float* __restrict__ final_threshold,
                float* __restrict__ out)
{
    const int b      = blockIdx.z;
    const int tile_x = blockIdx.x * TW;
    const int tile_y = blockIdx.y * TH;
    const float* m = mask + (size_t)b * (HH * WW);

    const float bsf    = blur_strength[b];
    const float esf    = edge_sensitivity[b];
    const float fthr   = final_threshold[b];
    const float ethr   = 0.5f * esf;          // exact in f32
    const float bff    = bsf / 3.0f;
    const float onembf = 1.0f - bff;
    const float w25f   = 1.0f / 25.0f;

    // thread -> 4 cols x 4 rows micro-tile, read straight from global
    const int tx = threadIdx.x & 31;          // col group
    const int ty = threadIdx.x >> 5;          // row group
    const int x0 = tile_x + 4 * tx;           // first output col (mult of 4)
    const int y0 = tile_y + 4 * ty;           // first output row

    const bool lok = (x0 > 0);                // left  float2 in-bounds?
    const bool rok = (x0 < WW - 4);           // right float2 in-bounds?

    // ---- phase 1: issue ALL 24 independent global loads (8 rows x 3) ----
    float2 u0[8];   // cols x0-2, x0-1
    float4 u1[8];   // cols x0 .. x0+3  (centers live here)
    float2 u2[8];   // cols x0+4, x0+5
    #pragma unroll
    for (int k = 0; k < 8; ++k) {
        const int gy = y0 - 2 + k;
        const float* rp = m + (size_t)gy * WW + x0;
        const bool rv = (unsigned)gy < (unsigned)HH;
        u0[k] = make_float2(0.f, 0.f);
        u1[k] = make_float4(0.f, 0.f, 0.f, 0.f);
        u2[k] = make_float2(0.f, 0.f);
        if (rv) {
            if (lok) u0[k] = *(const float2*)(rp - 2);   // 8B aligned
            u1[k] = *(const float4*)rp;                  // 16B aligned
            if (rok) u2[k] = *(const float2*)(rp + 4);   // 8B aligned
        }
    }

    // ---- phase 2: horizontal rolling sums per row (consumes u0/u2) ----
    float h5[8][4], h3[8][4];
    #pragma unroll
    for (int k = 0; k < 8; ++k) {
        float a0 = u0[k].x, a1 = u0[k].y;
        float a2 = u1[k].x, a3 = u1[k].y, a4 = u1[k].z, a5 = u1[k].w;
        float a6 = u2[k].x, a7 = u2[k].y;
        float s5 = ((a0 + a1) + (a2 + a3)) + a4;
        h5[k][0] = s5; s5 = s5 - a0 + a5;
        h5[k][1] = s5; s5 = s5 - a1 + a6;
        h5[k][2] = s5; s5 = s5 - a2 + a7;
        h5[k][3] = s5;
        float s3 = (a1 + a2) + a3;
        h3[k][0] = s3; s3 = s3 - a1 + a4;
        h3[k][1] = s3; s3 = s3 - a2 + a5;
        h3[k][2] = s3; s3 = s3 - a3 + a6;
        h3[k][3] = s3;
    }

    // ---- phase 3: epilogue, 4 output rows x 4 cols ----
    float* op = out + (size_t)b * (HH * WW) + (size_t)y0 * WW + x0;

    #pragma unroll
    for (int r = 0; r < 4; ++r) {
        f32x4 ov;
        #pragma unroll
        for (int c = 0; c < 4; ++c) {
            float sum25  = ((h5[r][c] + h5[r + 1][c]) + (h5[r + 2][c] + h5[r + 3][c]))
                         + h5[r + 4][c];
            float s9     = h3[r + 1][c] + h3[r + 2][c] + h3[r + 3][c];
            float center = (&u1[r + 2].x)[c];     // col x0+c of center row

            float edges  = fabsf(9.0f * center - s9);
            float sbase  = sum25 * w25f;
            float smooth = center * onembf + sbase * bff;

            bool isedge = edges > ethr;
            // no-edge branch compares EXACT center vs EXACT fthr -> always safe
            bool conf = (fabsf(edges - ethr) > EPS1) &&
                        (!isedge || (fabsf(smooth - fthr) > EPS2));
            float res = isedge ? smooth : center;
            float o   = (res > fthr) ? 1.0f : 0.0f;

            if (!conf)
                o = aes_exact_g(m, y0 + r, x0 + c, bsf, esf, fthr);

            ov[c] = o;          // c is compile-time after unroll
        }
        __builtin_nontemporal_store(ov, (f32x4*)(op + (size_t)r * WW));
    }
}

extern "C" void kernel_launch(void* const* d_in, const int* in_sizes, int n_in,
                              void* d_out, int out_size, void* d_ws, size_t ws_size,
                              hipStream_t stream) {
    const float* mask = (const float*)d_in[0];
    const float* bs   = (const float*)d_in[1];
    const float* es   = (const float*)d_in[2];
    const float* ft   = (const float*)d_in[3];
    float* out = (float*)d_out;

    dim3 grid(WW / TW, HH / TH, NB);   // 8 x 32 x 16 = 4096 blocks
    aes_kernel<<<grid, 256, 0, stream>>>(mask, bs, es, ft, out);
}

// Round 10
// 42.755 us; speedup vs baseline: 1.6069x; 1.6069x over previous
//
#include <hip/hip_runtime.h>

#define NB 16
#define HH 1024
#define WW 1024
#define TW 64          // tile width  (output)
#define TH 32          // tile height (output)
#define LC 72          // staged cols: global x in [tile_x-4, tile_x+68)
#define LR 36          // staged rows: global y in [tile_y-2, tile_y+34)
#define N4 (LR * (LC / 4))   // float4 staging ops = 648
#define NTHR 128

#define EPS1 2e-4f     // edge-threshold confidence margin (f32 err bound ~4e-6)
#define EPS2 1e-4f     // final-threshold confidence margin (f32 err bound ~4e-6)

typedef float f32x4 __attribute__((ext_vector_type(4)));

// Cold exact-path: recompute one pixel in f64 from LDS (identical math to the
// R1 kernel that scored absmax 0.0 against the np/f64 reference).
__device__ __noinline__ float aes_exact(const float (*raw)[LC], int lr, int lc,
                                        float bsf, float esf, float fthr)
{
    const double bfd   = (double)bsf / 3.0;
    const double ethrd = 0.5 * (double)esf;
    const double fthrd = (double)fthr;
    const double w25d  = (double)(1.0f / 25.0f);

    double s25 = 0.0, s9 = 0.0;
    for (int dy = 0; dy < 5; ++dy)
        for (int dx = 0; dx < 5; ++dx) {
            double v = (double)raw[lr + dy][lc + dx];
            s25 += v;
            if (dy >= 1 && dy <= 3 && dx >= 1 && dx <= 3) s9 += v;
        }
    double c      = (double)raw[lr + 2][lc + 2];
    double edges  = fabs(9.0 * c - s9);
    double sbase  = s25 * w25d;
    double smooth = c * (1.0 - bfd) + sbase * bfd;
    double result = (edges > ethrd) ? smooth : c;
    return (result > fthrd) ? 1.0f : 0.0f;
}

__global__ __launch_bounds__(NTHR)
void aes_kernel(const float* __restrict__ mask,
                const float* __restrict__ blur_strength,
                const float* __restrict__ edge_sensitivity,
                const float* __restrict__ final_threshold,
                float* __restrict__ out)
{
    __shared__ float raw[LR][LC];   // 10,368 B -> ~15 blocks/CU, ~30 waves/CU

    const int b      = blockIdx.z;
    const int tile_x = blockIdx.x * TW;
    const int tile_y = blockIdx.y * TH;
    const float* m = mask + (size_t)b * (HH * WW);

    // ---- stage tile + halo as float4; every float4 fully in or out of bounds
    for (int i = threadIdx.x; i < N4; i += NTHR) {
        int row = i / (LC / 4);
        int c4  = i - row * (LC / 4);
        int gy  = tile_y - 2 + row;
        int gx  = tile_x - 4 + 4 * c4;     // multiple of 4 -> 16B aligned
        f32x4 v = {0.f, 0.f, 0.f, 0.f};
        if ((unsigned)gy < (unsigned)HH && (unsigned)gx < (unsigned)WW)
            v = *(const f32x4*)(m + (size_t)gy * WW + gx);
        *(f32x4*)&raw[row][4 * c4] = v;
    }
    __syncthreads();

    const float bsf    = blur_strength[b];
    const float esf    = edge_sensitivity[b];
    const float fthr   = final_threshold[b];
    const float ethr   = 0.5f * esf;          // exact in f32
    const float bff    = bsf / 3.0f;
    const float onembf = 1.0f - bff;
    const float w25f   = 1.0f / 25.0f;

    // thread -> 4 cols x 4 rows micro-tile
    const int tx  = threadIdx.x & 15;         // col group (16 groups * 4 = 64)
    const int ty  = threadIdx.x >> 4;         // row group (8 groups * 4 = 32)
    const int lr0 = ty * 4;                   // LDS row of first window row
    const int lc0 = 4 * tx + 2;               // LDS col of (x0-2)

    // rolling ring over 5 raw rows; [ring][col]
    float h5[5][4], h3[5][4], cc[5][4];

    // loads 8 contiguous floats a0..a7 = global cols x0-2 .. x0+5 of one row,
    // builds rolling horizontal sums for the 4 output columns
#define LOADROW(ROWIDX, K)                                                  \
    {                                                                       \
        const float* rp = &raw[(ROWIDX)][0];                                \
        float2 u0 = *(const float2*)(rp + lc0);        /* 8B aligned  */    \
        float4 u1 = *(const float4*)(rp + lc0 + 2);    /* 16B aligned */    \
        float2 u2 = *(const float2*)(rp + lc0 + 6);    /* 8B aligned  */    \
        float a0 = u0.x, a1 = u0.y, a2 = u1.x, a3 = u1.y;                   \
        float a4 = u1.z, a5 = u1.w, a6 = u2.x, a7 = u2.y;                   \
        float s5 = ((a0 + a1) + (a2 + a3)) + a4;                            \
        h5[(K)][0] = s5; s5 = s5 - a0 + a5;                                 \
        h5[(K)][1] = s5; s5 = s5 - a1 + a6;                                 \
        h5[(K)][2] = s5; s5 = s5 - a2 + a7;                                 \
        h5[(K)][3] = s5;                                                    \
        float s3 = (a1 + a2) + a3;                                          \
        h3[(K)][0] = s3; s3 = s3 - a1 + a4;                                 \
        h3[(K)][1] = s3; s3 = s3 - a2 + a5;                                 \
        h3[(K)][2] = s3; s3 = s3 - a3 + a6;                                 \
        h3[(K)][3] = s3;                                                    \
        cc[(K)][0] = a2; cc[(K)][1] = a3; cc[(K)][2] = a4; cc[(K)][3] = a5; \
    }

    #pragma unroll
    for (int k = 0; k < 4; ++k)
        LOADROW(lr0 + k, k)

    float* op = out + (size_t)b * (HH * WW)
                    + (size_t)(tile_y + ty * 4) * WW + tile_x + 4 * tx;

    #pragma unroll
    for (int r = 0; r < 4; ++r) {
        LOADROW(lr0 + r + 4, (r + 4) % 5)
        const int i0 = r % 5, i1 = (r + 1) % 5, i2 = (r + 2) % 5;
        const int i3 = (r + 3) % 5, i4 = (r + 4) % 5;

        f32x4 ov;
        #pragma unroll
        for (int c = 0; c < 4; ++c) {
            float sum25  = ((h5[i0][c] + h5[i1][c]) + (h5[i2][c] + h5[i3][c])) + h5[i4][c];
            float s9     = h3[i1][c] + h3[i2][c] + h3[i3][c];
            float center = cc[i2][c];

            float edges  = fabsf(9.0f * center - s9);
            float sbase  = sum25 * w25f;
            float smooth = center * onembf + sbase * bff;

            bool isedge = edges > ethr;
            // no-edge branch compares EXACT center vs EXACT fthr -> always safe
            bool conf = (fabsf(edges - ethr) > EPS1) &&
                        (!isedge || (fabsf(smooth - fthr) > EPS2));
            float res = isedge ? smooth : center;
            float o   = (res > fthr) ? 1.0f : 0.0f;

            if (!conf)
                o = aes_exact(raw, lr0 + r, lc0 + c, bsf, esf, fthr);

            ov[c] = o;          // c is compile-time after unroll
        }
        *(f32x4*)(op + (size_t)r * WW) = ov;
    }
#undef LOADROW
}

extern "C" void kernel_launch(void* const* d_in, const int* in_sizes, int n_in,
                              void* d_out, int out_size, void* d_ws, size_t ws_size,
                              hipStream_t stream) {
    const float* mask = (const float*)d_in[0];
    const float* bs   = (const float*)d_in[1];
    const float* es   = (const float*)d_in[2];
    const float* ft   = (const float*)d_in[3];
    float* out = (float*)d_out;

    dim3 grid(WW / TW, HH / TH, NB);   // 16 x 32 x 16 = 8192 blocks
    aes_kernel<<<grid, NTHR, 0, stream>>>(mask, bs, es, ft, out);
}

// Round 11
// 41.391 us; speedup vs baseline: 1.6598x; 1.0329x over previous
//
#include <hip/hip_runtime.h>

#define NB 16
#define HH 1024
#define WW 1024
#define TW 128         // tile width  (output)
#define TH 32          // tile height (output)
#define LC 136         // staged cols: global x in [tile_x-4, tile_x+132)
#define LR 36          // staged rows: global y in [tile_y-2, tile_y+34)
#define C4 (LC / 4)    // 34 float4 groups per row
#define N4 (LR * C4)   // 1224 float4 groups per tile
#define GRIDX (WW / TW)        // 8
#define GRIDY (HH / (2 * TH))  // 16

#define EPS1 2e-4f     // edge-threshold confidence margin (f32 err bound ~4e-6)
#define EPS2 1e-4f     // final-threshold confidence margin (f32 err bound ~4e-6)

typedef float f32x4 __attribute__((ext_vector_type(4)));

__device__ __forceinline__ void gload_lds16(const float* g, float* l) {
#if __has_builtin(__builtin_amdgcn_global_load_lds)
    __builtin_amdgcn_global_load_lds(
        (const __attribute__((address_space(1))) void*)g,
        (__attribute__((address_space(3))) void*)l, 16, 0, 0);
#else
    *(f32x4*)l = *(const f32x4*)g;
#endif
}

// Cold exact-path: recompute one pixel in f64 from LDS (identical math to the
// R1 kernel that scored absmax 0.0 against the np/f64 reference).
__device__ __noinline__ float aes_exact(const float (*raw)[LC], int lr, int lc,
                                        float bsf, float esf, float fthr)
{
    const double bfd   = (double)bsf / 3.0;
    const double ethrd = 0.5 * (double)esf;
    const double fthrd = (double)fthr;
    const double w25d  = (double)(1.0f / 25.0f);

    double s25 = 0.0, s9 = 0.0;
    for (int dy = 0; dy < 5; ++dy)
        for (int dx = 0; dx < 5; ++dx) {
            double v = (double)raw[lr + dy][lc + dx];
            s25 += v;
            if (dy >= 1 && dy <= 3 && dx >= 1 && dx <= 3) s9 += v;
        }
    double c      = (double)raw[lr + 2][lc + 2];
    double edges  = fabs(9.0 * c - s9);
    double sbase  = s25 * w25d;
    double smooth = c * (1.0 - bfd) + sbase * bfd;
    double result = (edges > ethrd) ? smooth : c;
    return (result > fthrd) ? 1.0f : 0.0f;
}

__global__ __launch_bounds__(256)
void aes_kernel(const float* __restrict__ mask,
                const float* __restrict__ blur_strength,
                const float* __restrict__ edge_sensitivity,
                const float* __restrict__ final_threshold,
                float* __restrict__ out)
{
    __shared__ float raw[2][LR][LC];   // 39,168 B

    const int b      = blockIdx.z;
    const int tile_x = blockIdx.x * TW;
    const int sy0    = blockIdx.y * (2 * TH);   // vertical pair: sy0, sy0+TH
    const float* m = mask + (size_t)b * (HH * WW);

    const float bsf    = blur_strength[b];
    const float esf    = edge_sensitivity[b];
    const float fthr   = final_threshold[b];
    const float ethr   = 0.5f * esf;          // exact in f32
    const float bff    = bsf / 3.0f;
    const float onembf = 1.0f - bff;
    const float w25f   = 1.0f / 25.0f;

    // thread -> 4 cols x 4 rows micro-tile
    const int tx  = threadIdx.x & 31;
    const int ty  = threadIdx.x >> 5;
    const int lr0 = ty * 4;
    const int lc0 = 4 * tx + 2;

    // all staged addresses of BOTH tiles in-bounds?  (block-uniform)
    const bool interior = (blockIdx.x >= 1) & (blockIdx.x <= GRIDX - 2)
                        & (blockIdx.y >= 1) & (blockIdx.y <= GRIDY - 2);

    // ---- async DMA staging of one tile into LDS buffer (interior only) ----
#define STAGE_DMA(TY, BUF)                                                  \
    {                                                                       \
        _Pragma("unroll")                                                   \
        for (int k = 0; k < 5; ++k) {                                       \
            int i = (int)threadIdx.x + k * 256;                             \
            if (i < N4) {                                                   \
                int row = i / C4, c4 = i - row * C4;                        \
                gload_lds16(m + (size_t)((TY) - 2 + row) * WW               \
                              + (tile_x - 4 + 4 * c4),                      \
                            &raw[(BUF)][0][0] + (size_t)i * 4);             \
            }                                                               \
        }                                                                   \
    }

    // ---- masked reg staging (boundary blocks; zeros for SAME padding) ----
#define STAGE_LOAD(TY)                                                      \
    {                                                                       \
        _Pragma("unroll")                                                   \
        for (int k = 0; k < 5; ++k) {                                       \
            int i = (int)threadIdx.x + k * 256;                             \
            f32x4 v = {0.f, 0.f, 0.f, 0.f};                                 \
            if (i < N4) {                                                   \
                int row = i / C4, c4 = i - row * C4;                        \
                int gy = (TY) - 2 + row;                                    \
                int gx = tile_x - 4 + 4 * c4;                               \
                if ((unsigned)gy < (unsigned)HH && (unsigned)gx < (unsigned)WW) \
                    v = *(const f32x4*)(m + (size_t)gy * WW + gx);          \
            }                                                               \
            stg[k] = v;                                                     \
        }                                                                   \
    }

#define STAGE_WRITE(BUF)                                                    \
    {                                                                       \
        _Pragma("unroll")                                                   \
        for (int k = 0; k < 5; ++k) {                                       \
            int i = (int)threadIdx.x + k * 256;                             \
            if (i < N4) {                                                   \
                int row = i / C4, c4 = i - row * C4;                        \
                *(f32x4*)&raw[(BUF)][row][4 * c4] = stg[k];                 \
            }                                                               \
        }                                                                   \
    }

#define LOADROW(RB, ROWIDX, K)                                              \
    {                                                                       \
        const float* rp = &RB[(ROWIDX)][0];                                 \
        float2 u0 = *(const float2*)(rp + lc0);        /* 8B aligned  */    \
        float4 u1 = *(const float4*)(rp + lc0 + 2);    /* 16B aligned */    \
        float2 u2 = *(const float2*)(rp + lc0 + 6);    /* 8B aligned  */    \
        float a0 = u0.x, a1 = u0.y, a2 = u1.x, a3 = u1.y;                   \
        float a4 = u1.z, a5 = u1.w, a6 = u2.x, a7 = u2.y;                   \
        float s5 = ((a0 + a1) + (a2 + a3)) + a4;                            \
        h5[(K)][0] = s5; s5 = s5 - a0 + a5;                                 \
        h5[(K)][1] = s5; s5 = s5 - a1 + a6;                                 \
        h5[(K)][2] = s5; s5 = s5 - a2 + a7;                                 \
        h5[(K)][3] = s5;                                                    \
        float s3 = (a1 + a2) + a3;                                          \
        h3[(K)][0] = s3; s3 = s3 - a1 + a4;                                 \
        h3[(K)][1] = s3; s3 = s3 - a2 + a5;                                 \
        h3[(K)][2] = s3; s3 = s3 - a3 + a6;                                 \
        h3[(K)][3] = s3;                                                    \
        cc[(K)][0] = a2; cc[(K)][1] = a3; cc[(K)][2] = a4; cc[(K)][3] = a5; \
    }

    // ---- compute one tile from LDS into OVV[0..3] (no stores) ----
#define COMPUTE_VALS(BUF, OVV)                                              \
    {                                                                       \
        const float (*rb)[LC] = raw[(BUF)];                                 \
        float h5[5][4], h3[5][4], cc[5][4];                                 \
        _Pragma("unroll")                                                   \
        for (int k = 0; k < 4; ++k)                                         \
            LOADROW(rb, lr0 + k, k)                                         \
        _Pragma("unroll")                                                   \
        for (int r = 0; r < 4; ++r) {                                       \
            LOADROW(rb, lr0 + r + 4, (r + 4) % 5)                           \
            const int i0 = r % 5, i1 = (r + 1) % 5, i2 = (r + 2) % 5;       \
            const int i3 = (r + 3) % 5, i4 = (r + 4) % 5;                   \
            _Pragma("unroll")                                               \
            for (int c = 0; c < 4; ++c) {                                   \
                float sum25  = ((h5[i0][c] + h5[i1][c])                     \
                              + (h5[i2][c] + h5[i3][c])) + h5[i4][c];       \
                float s9     = h3[i1][c] + h3[i2][c] + h3[i3][c];           \
                float center = cc[i2][c];                                   \
                float edges  = fabsf(9.0f * center - s9);                   \
                float sbase  = sum25 * w25f;                                \
                float smooth = center * onembf + sbase * bff;               \
                bool isedge = edges > ethr;                                 \
                bool conf = (fabsf(edges - ethr) > EPS1) &&                 \
                            (!isedge || (fabsf(smooth - fthr) > EPS2));     \
                float res = isedge ? smooth : center;                       \
                float o   = (res > fthr) ? 1.0f : 0.0f;                     \
                if (!conf)                                                  \
                    o = aes_exact(rb, lr0 + r, lc0 + c, bsf, esf, fthr);    \
                OVV[r][c] = o;                                              \
            }                                                               \
        }                                                                   \
    }

#define STORE_VALS(TY, OVV)                                                 \
    {                                                                       \
        float* op = out + (size_t)b * (HH * WW)                             \
                        + (size_t)((TY) + ty * 4) * WW + tile_x + 4 * tx;   \
        _Pragma("unroll")                                                   \
        for (int r = 0; r < 4; ++r)                                         \
            *(f32x4*)(op + (size_t)r * WW) = OVV[r];                        \
    }

    f32x4 ov0[4], ov1[4];

    if (interior) {
        // async-DMA double-buffered pipeline: DMA1 flies under compute0;
        // tile0 stores deferred past the barrier so the drain waits DMA only.
        STAGE_DMA(sy0, 0)
        __syncthreads();                 // drain DMA0
        STAGE_DMA(sy0 + TH, 1)           // issue; hides under compute0
        COMPUTE_VALS(0, ov0)
        __syncthreads();                 // drain DMA1 (no stores outstanding)
        STORE_VALS(sy0, ov0)
        COMPUTE_VALS(1, ov1)
        STORE_VALS(sy0 + TH, ov1)
    } else {
        // proven R7 reg-staged dbuf path (handles SAME-padding zeros)
        f32x4 stg[5];
        STAGE_LOAD(sy0)
        STAGE_WRITE(0)
        __syncthreads();
        STAGE_LOAD(sy0 + TH)             // loads fly under compute0
        COMPUTE_VALS(0, ov0)
        STAGE_WRITE(1)
        __syncthreads();
        STORE_VALS(sy0, ov0)
        COMPUTE_VALS(1, ov1)
        STORE_VALS(sy0 + TH, ov1)
    }

#undef STAGE_DMA
#undef STAGE_LOAD
#undef STAGE_WRITE
#undef LOADROW
#undef COMPUTE_VALS
#undef STORE_VALS
}

extern "C" void kernel_launch(void* const* d_in, const int* in_sizes, int n_in,
                              void* d_out, int out_size, void* d_ws, size_t ws_size,
                              hipStream_t stream) {
    const float* mask = (const float*)d_in[0];
    const float* bs   = (const float*)d_in[1];
    const float* es   = (const float*)d_in[2];
    const float* ft   = (const float*)d_in[3];
    float* out = (float*)d_out;

    dim3 grid(GRIDX, GRIDY, NB);   // 8 x 16 x 16 = 2048 blocks
    aes_kernel<<<grid, 256, 0, stream>>>(mask, bs, es, ft, out);
}